// Round 7
// baseline (304.649 us; speedup 1.0000x reference)
//
#include <hip/hip_runtime.h>
#include <math.h>

#define B_  8
#define T_  2048
#define S_  2048
#define D_  512

typedef _Float16 half8   __attribute__((ext_vector_type(8)));
typedef _Float16 half4_t __attribute__((ext_vector_type(4)));
typedef float    floatx4 __attribute__((ext_vector_type(4)));

__device__ __forceinline__ floatx4 mfma16(half8 a, half8 b, floatx4 c) {
  return __builtin_amdgcn_mfma_f32_16x16x32_f16(a, b, c, 0, 0, 0);
}

// async global->LDS, 16B per lane; lds base must be wave-uniform (HW adds lane*16)
__device__ __forceinline__ void async16(void* lds, const void* g) {
  __builtin_amdgcn_global_load_lds(
      (const __attribute__((address_space(1))) void*)g,
      (__attribute__((address_space(3))) void*)lds, 16, 0, 0);
}

// ---------------------------------------------------------------------------
// Kernel 1: Vt[b][d][s] = (fp16) attn[b][s][d]
// ---------------------------------------------------------------------------
__global__ __launch_bounds__(256) void transpose_cast_kernel(
    const float* __restrict__ attn, _Float16* __restrict__ Vt) {
  __shared__ _Float16 tile[32][33];
  const int tx = threadIdx.x, ty = threadIdx.y;
  const int b = blockIdx.z, s0 = blockIdx.y * 32, d0 = blockIdx.x * 32;
  const float* src = attn + ((size_t)b * S_ + s0) * D_ + d0;
#pragma unroll
  for (int i = 0; i < 4; ++i) {
    int s = ty + i * 8;
    tile[tx][s] = (_Float16)src[(size_t)s * D_ + tx];
  }
  __syncthreads();
  _Float16* dst = Vt + ((size_t)b * D_ + d0) * S_ + s0;
#pragma unroll
  for (int i = 0; i < 4; ++i) {
    int d = ty + i * 8;
    dst[(size_t)d * S_ + tx] = tile[d][tx];
  }
}

// ---------------------------------------------------------------------------
// Kernel 2: K16[i][e] = (fp16)( sum_d attn[i][d] * W[e][d] + bias[e] )
// ---------------------------------------------------------------------------
__global__ __launch_bounds__(512, 2) void keys_gemm_kernel(
    const float* __restrict__ X, const float* __restrict__ W,
    const float* __restrict__ bias, _Float16* __restrict__ K16) {
  __shared__ alignas(16) _Float16 Xs[128][72];
  __shared__ alignas(16) _Float16 Ws[128][72];
  const int t = threadIdx.x;
  const int wave = t >> 6, lane = t & 63, q = lane >> 4, n = lane & 15;
  const int wm = wave >> 2, wn = wave & 3;
  const int m0 = blockIdx.x * 128, n0 = blockIdx.y * 128;

  floatx4 acc[4][2];
#pragma unroll
  for (int i = 0; i < 4; ++i)
#pragma unroll
    for (int j = 0; j < 2; ++j) {
      floatx4 z = {0.f, 0.f, 0.f, 0.f};
      acc[i][j] = z;
    }

  for (int kc = 0; kc < 8; ++kc) {
    const int k0 = kc * 64;
#pragma unroll
    for (int i = 0; i < 4; ++i) {
      int seg = i * 512 + t;
      int row = seg >> 4, c4 = (seg & 15) * 4;
      floatx4 xv = *(const floatx4*)&X[(size_t)(m0 + row) * D_ + k0 + c4];
      floatx4 wv = *(const floatx4*)&W[(size_t)(n0 + row) * D_ + k0 + c4];
      half4_t xh, wh;
#pragma unroll
      for (int j = 0; j < 4; ++j) { xh[j] = (_Float16)xv[j]; wh[j] = (_Float16)wv[j]; }
      *(half4_t*)&Xs[row][c4] = xh;
      *(half4_t*)&Ws[row][c4] = wh;
    }
    __syncthreads();
#pragma unroll
    for (int kk = 0; kk < 2; ++kk) {
      half8 a[4], bb[2];
#pragma unroll
      for (int mt = 0; mt < 4; ++mt)
        a[mt] = *(const half8*)&Xs[wm * 64 + mt * 16 + n][kk * 32 + q * 8];
#pragma unroll
      for (int nt = 0; nt < 2; ++nt)
        bb[nt] = *(const half8*)&Ws[wn * 32 + nt * 16 + n][kk * 32 + q * 8];
#pragma unroll
      for (int mt = 0; mt < 4; ++mt)
#pragma unroll
        for (int nt = 0; nt < 2; ++nt)
          acc[mt][nt] = mfma16(a[mt], bb[nt], acc[mt][nt]);
    }
    __syncthreads();
  }

#pragma unroll
  for (int nt = 0; nt < 2; ++nt) {
    int col = n0 + wn * 32 + nt * 16 + n;
    float bv = bias[col];
#pragma unroll
    for (int mt = 0; mt < 4; ++mt)
#pragma unroll
      for (int r = 0; r < 4; ++r) {
        int row = m0 + wm * 64 + mt * 16 + q * 4 + r;
        K16[(size_t)row * D_ + col] = (_Float16)(acc[mt][nt][r] + bv);
      }
  }
}

// ---------------------------------------------------------------------------
// Kernel 3: flash attention — 512 thr / 8 waves, BM=64, BN=32.
//   WAVE-INDEPENDENT tiles: each wave (rg, h) computes the FULL 32-col QK^T
//   for rg's 16 rows (duplicated across the h-pair; MFMA is only ~16% busy),
//   so softmax/defer-max/P are wave-local — ZERO intra-tile barriers, only
//   the buffer-swap __syncthreads. The 2 waves/SIMD slip freely: one wave's
//   softmax/VALU overlaps the other's LDS/MFMA. PV stays d-split (wave owns
//   its 256-d half; l via ones-column MFMA; duplicate l identical per pair).
//   P scratch wave-private [8][16][40] with row-bit3 chunk XOR swizzle:
//   stored chunk = logical ^ ((row>>3)<<1) on write AND read — puts the four
//   qd-groups on disjoint bank octets (fixes the 80-word ≡ 16 mod 32 qd0/qd2
//   collision) while keeping b128 reads 16B-aligned.
//   Direct __shared__ indexing only (R4/R5 lesson: generic char* bases +
//   pointer-selects defeat InferAddressSpaces -> flat loads).
// ---------------------------------------------------------------------------
__global__ __launch_bounds__(512, 2) void flash_kernel(
    const float* __restrict__ Qf, const _Float16* __restrict__ K16,
    const _Float16* __restrict__ Vt, float* __restrict__ out) {
  // Klds row = 32 chunks of 16B, chunk slot l holds source chunk (l ^ (srow&7))
  __shared__ alignas(16) _Float16 Klds[2][32][512];
  // Vlds row (d) = 4 chunks of 16B, slot c holds source s-chunk (c ^ ((d>>1)&3))
  __shared__ alignas(16) _Float16 Vlds[2][512][32];
  __shared__ alignas(16) _Float16 Pp[8][16][40];   // wave-private P scratch

  const int t = threadIdx.x;
  const int w = t >> 6, lane = t & 63, qd = lane >> 4, n = lane & 15;
  const int n7 = n & 7;
  const int rg = w >> 1, h = w & 1;
  const int bid = blockIdx.x;
  const int b = bid & 7, t0 = (bid >> 3) * 64;

  const _Float16* Kb = K16 + (size_t)b * S_ * D_;
  const _Float16* Vb = Vt + (size_t)b * D_ * S_;

  const int vsw = (lane & 3) ^ ((lane >> 3) & 3);  // staging V source s-chunk
  const int ccV = qd ^ ((n >> 1) & 3);             // V read slot
  // P chunk swizzle constants
  const int psw = qd & 2;                          // write: ((row>>3)&1)<<1, row=qd*4+r
  const int prd = (qd ^ ((n & 8) >> 2)) * 8;       // read: chunk qd ^ ((n>>3)<<1)

  // ---- Q -> registers (row-group's 16 rows, full D; pair-redundant) ----
  half8 qreg[16];
  {
    const float* qrow = Qf + ((size_t)b * T_ + t0 + rg * 16 + n) * D_;
#pragma unroll
    for (int kk = 0; kk < 16; ++kk) {
      floatx4 v0 = *(const floatx4*)&qrow[kk * 32 + qd * 8];
      floatx4 v1 = *(const floatx4*)&qrow[kk * 32 + qd * 8 + 4];
      half8 hv;
#pragma unroll
      for (int j = 0; j < 4; ++j) { hv[j] = (_Float16)v0[j]; hv[j + 4] = (_Float16)v1[j]; }
      qreg[kk] = hv;
    }
  }

  floatx4 O[17];   // [0..15] = wave's 256-d half, [16] = l (ones column)
#pragma unroll
  for (int ng = 0; ng < 17; ++ng) {
    floatx4 z = {0.f, 0.f, 0.f, 0.f};
    O[ng] = z;
  }
  float m_st[4];
#pragma unroll
  for (int r = 0; r < 4; ++r) m_st[r] = -1e30f;

  half8 ones8;
#pragma unroll
  for (int j = 0; j < 8; ++j) ones8[j] = (_Float16)1.0f;

  // ---- prologue staging: K[0], V[0] (8 waves x 4 rows / 4 d-groups) ----
#pragma unroll
  for (int i = 0; i < 4; ++i) {
    int row = w * 4 + i;
    async16(&Klds[0][row][0], Kb + (size_t)row * D_ + ((lane ^ (row & 7)) * 8));
  }
#pragma unroll
  for (int i = 0; i < 4; ++i) {
    int d0 = (w * 4 + i) * 16;
    async16(&Vlds[0][d0][0], Vb + (size_t)(d0 + (lane >> 2)) * S_ + vsw * 8);
  }
  __syncthreads();

  for (int st = 0; st < S_ / 32; ++st) {
    const int cur = st & 1, nxt = cur ^ 1;
    const int s0 = st * 32;

    // ---- prefetch next K+V tile (in flight during whole compute phase) ----
    if (st < S_ / 32 - 1) {
#pragma unroll
      for (int i = 0; i < 4; ++i) {
        int row = w * 4 + i;
        async16(&Klds[nxt][row][0],
                Kb + (size_t)(s0 + 32 + row) * D_ + ((lane ^ (row & 7)) * 8));
      }
#pragma unroll
      for (int i = 0; i < 4; ++i) {
        int d0 = (w * 4 + i) * 16;
        async16(&Vlds[nxt][d0][0],
                Vb + (size_t)(d0 + (lane >> 2)) * S_ + s0 + 32 + vsw * 8);
      }
    }

    // ---- QK^T: wave's 16 rows x ALL 32 cols, K=512 (4 indep chains) ----
    floatx4 Sa0 = {0.f, 0.f, 0.f, 0.f}, Sa1 = Sa0, Sb0 = Sa0, Sb1 = Sa0;
#pragma unroll
    for (int kk = 0; kk < 8; ++kk) {
      int slot = (kk * 4 + qd) ^ n7;
      half8 b0 = *(const half8*)&Klds[cur][n][slot * 8];
      half8 b1 = *(const half8*)&Klds[cur][16 + n][slot * 8];
      Sa0 = mfma16(qreg[kk], b0, Sa0);
      Sa1 = mfma16(qreg[kk], b1, Sa1);
    }
#pragma unroll
    for (int kk = 8; kk < 16; ++kk) {
      int slot = (kk * 4 + qd) ^ n7;
      half8 b0 = *(const half8*)&Klds[cur][n][slot * 8];
      half8 b1 = *(const half8*)&Klds[cur][16 + n][slot * 8];
      Sb0 = mfma16(qreg[kk], b0, Sb0);
      Sb1 = mfma16(qreg[kk], b1, Sb1);
    }
    floatx4 Sc0 = Sa0 + Sb0, Sc1 = Sa1 + Sb1;

    // ---- wave-local row-max over all 32 cols; defer-max THR=8 ----
    float pm[4], need = 0.f;
#pragma unroll
    for (int r = 0; r < 4; ++r) {
      float v = fmaxf(Sc0[r], Sc1[r]);
      v = fmaxf(v, __shfl_xor(v, 1, 16));
      v = fmaxf(v, __shfl_xor(v, 2, 16));
      v = fmaxf(v, __shfl_xor(v, 4, 16));
      v = fmaxf(v, __shfl_xor(v, 8, 16));
      pm[r] = v;
      need = fmaxf(need, v - m_st[r]);
    }
    if (__any(need > 8.f)) {
#pragma unroll
      for (int r = 0; r < 4; ++r) {
        float mn = fmaxf(m_st[r], pm[r]);
        float al = __expf(m_st[r] - mn);
        m_st[r] = mn;
#pragma unroll
        for (int ng = 0; ng < 17; ++ng) O[ng][r] *= al;
      }
    }

    // ---- P = exp(S - m) -> wave-private scratch (chunk-swizzled) ----
#pragma unroll
    for (int r = 0; r < 4; ++r) {
      float p0 = __expf(Sc0[r] - m_st[r]);   // <= e^8, fp16-safe
      float p1 = __expf(Sc1[r] - m_st[r]);
      int sc0 = (n >> 3) ^ psw;              // logical chunk n>>3
      int sc1 = (2 | (n >> 3)) ^ psw;        // logical chunk 2+(n>>3)
      Pp[w][qd * 4 + r][sc0 * 8 + n7] = (_Float16)p0;
      Pp[w][qd * 4 + r][sc1 * 8 + n7] = (_Float16)p1;
    }
    half8 av = *(const half8*)&Pp[w][n][prd];

    // ---- PV: O[16 rows x 256-d half] += P(16x32) @ V(32x256), + l ----
#pragma unroll
    for (int ng = 0; ng < 16; ++ng) {
      half8 bv = *(const half8*)&Vlds[cur][h * 256 + ng * 16 + n][ccV * 8];
      O[ng] = mfma16(av, bv, O[ng]);
    }
    O[16] = mfma16(av, ones8, O[16]);

    if (st < S_ / 32 - 1) __syncthreads();  // swap buffers (drains prefetch)
  }

  // ---- epilogue: out = O / l for this wave's 256-d half ----
  float* ob = out + ((size_t)b * T_ + t0 + rg * 16) * D_ + h * 256;
#pragma unroll
  for (int r = 0; r < 4; ++r) {
    float inv = 1.f / O[16][r];
    const size_t rowoff = (size_t)(qd * 4 + r) * D_;
#pragma unroll
    for (int ng = 0; ng < 16; ++ng)
      ob[rowoff + ng * 16 + n] = O[ng][r] * inv;
  }
}

// ---------------------------------------------------------------------------
extern "C" void kernel_launch(void* const* d_in, const int* in_sizes, int n_in,
                              void* d_out, int out_size, void* d_ws, size_t ws_size,
                              hipStream_t stream) {
  (void)in_sizes; (void)n_in; (void)out_size; (void)ws_size;
  const float* main_in = (const float*)d_in[0];   // [B,T,D]
  const float* attn_in = (const float*)d_in[1];   // [B,S,D]
  const float* W_f     = (const float*)d_in[2];   // [D,D]
  const float* b_f     = (const float*)d_in[3];   // [D]
  float* out = (float*)d_out;                     // [B,T,D] fp32

  _Float16* K16 = (_Float16*)d_ws;                       // [B*S, D] fp16
  _Float16* Vt  = K16 + (size_t)B_ * S_ * D_;            // [B, D, S] fp16

  transpose_cast_kernel<<<dim3(D_ / 32, S_ / 32, B_), dim3(32, 8, 1), 0, stream>>>(
      attn_in, Vt);
  keys_gemm_kernel<<<dim3((B_ * S_) / 128, D_ / 128), 512, 0, stream>>>(
      attn_in, W_f, b_f, K16);
  flash_kernel<<<(B_ * T_) / 64, 512, 0, stream>>>(main_in, K16, Vt, out);
}

// Round 8
// 272.528 us; speedup vs baseline: 1.1179x; 1.1179x over previous
//
#include <hip/hip_runtime.h>
#include <math.h>

#define B_  8
#define T_  2048
#define S_  2048
#define D_  512

typedef _Float16 half8   __attribute__((ext_vector_type(8)));
typedef _Float16 half4_t __attribute__((ext_vector_type(4)));
typedef float    floatx4 __attribute__((ext_vector_type(4)));

__device__ __forceinline__ floatx4 mfma16(half8 a, half8 b, floatx4 c) {
  return __builtin_amdgcn_mfma_f32_16x16x32_f16(a, b, c, 0, 0, 0);
}

// async global->LDS, 16B per lane; lds base must be wave-uniform (HW adds lane*16)
__device__ __forceinline__ void async16(void* lds, const void* g) {
  __builtin_amdgcn_global_load_lds(
      (const __attribute__((address_space(1))) void*)g,
      (__attribute__((address_space(3))) void*)lds, 16, 0, 0);
}

// LDS-visibility barrier: drains lgkmcnt ONLY, so the global_load_lds
// prefetch stays in flight across it (drained by __syncthreads at tile end).
__device__ __forceinline__ void bar_lds() {
  __builtin_amdgcn_sched_barrier(0);
  asm volatile("s_waitcnt lgkmcnt(0)" ::: "memory");
  __builtin_amdgcn_s_barrier();
  __builtin_amdgcn_sched_barrier(0);
}

// ---------------------------------------------------------------------------
// Kernel 1: Vt[b][d][s] = (fp16) attn[b][s][d]
// ---------------------------------------------------------------------------
__global__ __launch_bounds__(256) void transpose_cast_kernel(
    const float* __restrict__ attn, _Float16* __restrict__ Vt) {
  __shared__ _Float16 tile[32][33];
  const int tx = threadIdx.x, ty = threadIdx.y;
  const int b = blockIdx.z, s0 = blockIdx.y * 32, d0 = blockIdx.x * 32;
  const float* src = attn + ((size_t)b * S_ + s0) * D_ + d0;
#pragma unroll
  for (int i = 0; i < 4; ++i) {
    int s = ty + i * 8;
    tile[tx][s] = (_Float16)src[(size_t)s * D_ + tx];
  }
  __syncthreads();
  _Float16* dst = Vt + ((size_t)b * D_ + d0) * S_ + s0;
#pragma unroll
  for (int i = 0; i < 4; ++i) {
    int d = ty + i * 8;
    dst[(size_t)d * S_ + tx] = tile[d][tx];
  }
}

// ---------------------------------------------------------------------------
// Kernel 2: K16[i][e] = (fp16)( sum_d attn[i][d] * W[e][d] + bias[e] )
// ---------------------------------------------------------------------------
__global__ __launch_bounds__(512, 2) void keys_gemm_kernel(
    const float* __restrict__ X, const float* __restrict__ W,
    const float* __restrict__ bias, _Float16* __restrict__ K16) {
  __shared__ alignas(16) _Float16 Xs[128][72];
  __shared__ alignas(16) _Float16 Ws[128][72];
  const int t = threadIdx.x;
  const int wave = t >> 6, lane = t & 63, q = lane >> 4, n = lane & 15;
  const int wm = wave >> 2, wn = wave & 3;
  const int m0 = blockIdx.x * 128, n0 = blockIdx.y * 128;

  floatx4 acc[4][2];
#pragma unroll
  for (int i = 0; i < 4; ++i)
#pragma unroll
    for (int j = 0; j < 2; ++j) {
      floatx4 z = {0.f, 0.f, 0.f, 0.f};
      acc[i][j] = z;
    }

  for (int kc = 0; kc < 8; ++kc) {
    const int k0 = kc * 64;
#pragma unroll
    for (int i = 0; i < 4; ++i) {
      int seg = i * 512 + t;
      int row = seg >> 4, c4 = (seg & 15) * 4;
      floatx4 xv = *(const floatx4*)&X[(size_t)(m0 + row) * D_ + k0 + c4];
      floatx4 wv = *(const floatx4*)&W[(size_t)(n0 + row) * D_ + k0 + c4];
      half4_t xh, wh;
#pragma unroll
      for (int j = 0; j < 4; ++j) { xh[j] = (_Float16)xv[j]; wh[j] = (_Float16)wv[j]; }
      *(half4_t*)&Xs[row][c4] = xh;
      *(half4_t*)&Ws[row][c4] = wh;
    }
    __syncthreads();
#pragma unroll
    for (int kk = 0; kk < 2; ++kk) {
      half8 a[4], bb[2];
#pragma unroll
      for (int mt = 0; mt < 4; ++mt)
        a[mt] = *(const half8*)&Xs[wm * 64 + mt * 16 + n][kk * 32 + q * 8];
#pragma unroll
      for (int nt = 0; nt < 2; ++nt)
        bb[nt] = *(const half8*)&Ws[wn * 32 + nt * 16 + n][kk * 32 + q * 8];
#pragma unroll
      for (int mt = 0; mt < 4; ++mt)
#pragma unroll
        for (int nt = 0; nt < 2; ++nt)
          acc[mt][nt] = mfma16(a[mt], bb[nt], acc[mt][nt]);
    }
    __syncthreads();
  }

#pragma unroll
  for (int nt = 0; nt < 2; ++nt) {
    int col = n0 + wn * 32 + nt * 16 + n;
    float bv = bias[col];
#pragma unroll
    for (int mt = 0; mt < 4; ++mt)
#pragma unroll
      for (int r = 0; r < 4; ++r) {
        int row = m0 + wm * 64 + mt * 16 + q * 4 + r;
        K16[(size_t)row * D_ + col] = (_Float16)(acc[mt][nt][r] + bv);
      }
  }
}

// ---------------------------------------------------------------------------
// Kernel 3: flash attention — 512 thr / 8 waves, BM=64, BN=32.
//   R6 structure + single-exchange softmax (3 -> 2 barriers/tile, ZERO
//   traffic change; R2/R7 lesson: never trade +LDS-reads for -barriers).
//   Pre-barrier: each wave computes LOCAL tile-max mloc, writes
//   P_loc = exp(S - mloc) (<=1, fp16-safe) and publishes mloc; also
//   publishes last tile's running max to Mrun (one-tile-late to avoid a
//   same-phase read/write race). Post-barrier: lanes read m0/m1/mrun[n]
//   (shared values only -> pair-consistent __any defer decision, THR=8),
//   fold the correction into ONE fp16 scalar on the PV A-frag:
//   av' = av * e^{mloc_h' - m_used}, h' = qd>>1 (each av chunk belongs to
//   exactly one half's columns). O/l stay consistently scaled; O-rescale
//   only when fired (alpha via 4 shfls from row-owner lanes).
//   Direct __shared__ indexing only (R4/R5: generic char* bases defeat
//   InferAddressSpaces -> flat loads).
// ---------------------------------------------------------------------------
__global__ __launch_bounds__(512, 2) void flash_kernel(
    const float* __restrict__ Qf, const _Float16* __restrict__ K16,
    const _Float16* __restrict__ Vt, float* __restrict__ out) {
  // Klds row = 32 chunks of 16B, chunk slot l holds source chunk (l ^ (srow&7))
  __shared__ alignas(16) _Float16 Klds[2][32][512];
  // Vlds row (d) = 4 chunks of 16B, slot c holds source s-chunk (c ^ ((d>>1)&3))
  __shared__ alignas(16) _Float16 Vlds[2][512][32];
  __shared__ alignas(16) _Float16 Pscr[4][16][40];  // per-row-group shared P
  __shared__ float Mscr[4][2][16];                  // per-(rg,h) local tile max
  __shared__ float Mrun[4][16];                     // per-rg running max (1-late)

  const int t = threadIdx.x;
  const int w = t >> 6, lane = t & 63, qd = lane >> 4, n = lane & 15;
  const int n7 = n & 7;
  const int rg = w >> 1, h = w & 1;
  const int bid = blockIdx.x;
  const int b = bid & 7, t0 = (bid >> 3) * 64;

  const _Float16* Kb = K16 + (size_t)b * S_ * D_;
  const _Float16* Vb = Vt + (size_t)b * D_ * S_;

  const int vsw = (lane & 3) ^ ((lane >> 3) & 3);  // staging V source s-chunk
  const int ccV = qd ^ ((n >> 1) & 3);             // V read slot

  // ---- Q -> registers (row-group's 16 rows, full D; pair-redundant) ----
  half8 qreg[16];
  {
    const float* qrow = Qf + ((size_t)b * T_ + t0 + rg * 16 + n) * D_;
#pragma unroll
    for (int kk = 0; kk < 16; ++kk) {
      floatx4 v0 = *(const floatx4*)&qrow[kk * 32 + qd * 8];
      floatx4 v1 = *(const floatx4*)&qrow[kk * 32 + qd * 8 + 4];
      half8 hv;
#pragma unroll
      for (int j = 0; j < 4; ++j) { hv[j] = (_Float16)v0[j]; hv[j + 4] = (_Float16)v1[j]; }
      qreg[kk] = hv;
    }
  }

  floatx4 O[17];   // [0..15] = wave's 256-d half, [16] = l (ones column)
#pragma unroll
  for (int ng = 0; ng < 17; ++ng) {
    floatx4 z = {0.f, 0.f, 0.f, 0.f};
    O[ng] = z;
  }
  float m_st[4];   // running max for rows qd*4+r (mirrors Mrun)
#pragma unroll
  for (int r = 0; r < 4; ++r) m_st[r] = -1e30f;
  float muL = -1e30f;   // per-lane latched running max for row n (1-late pub)

  half8 ones8;
#pragma unroll
  for (int j = 0; j < 8; ++j) ones8[j] = (_Float16)1.0f;

  // ---- prologue staging: K[0], V[0] (8 waves x 4 rows / 4 d-groups) ----
#pragma unroll
  for (int i = 0; i < 4; ++i) {
    int row = w * 4 + i;
    async16(&Klds[0][row][0], Kb + (size_t)row * D_ + ((lane ^ (row & 7)) * 8));
  }
#pragma unroll
  for (int i = 0; i < 4; ++i) {
    int d0 = (w * 4 + i) * 16;
    async16(&Vlds[0][d0][0], Vb + (size_t)(d0 + (lane >> 2)) * S_ + vsw * 8);
  }
  __syncthreads();

  for (int st = 0; st < S_ / 32; ++st) {
    const int cur = st & 1, nxt = cur ^ 1;
    const int s0 = st * 32;

    // ---- prefetch next K+V tile (in flight across the exchange barrier) ----
    if (st < S_ / 32 - 1) {
#pragma unroll
      for (int i = 0; i < 4; ++i) {
        int row = w * 4 + i;
        async16(&Klds[nxt][row][0],
                Kb + (size_t)(s0 + 32 + row) * D_ + ((lane ^ (row & 7)) * 8));
      }
#pragma unroll
      for (int i = 0; i < 4; ++i) {
        int d0 = (w * 4 + i) * 16;
        async16(&Vlds[nxt][d0][0],
                Vb + (size_t)(d0 + (lane >> 2)) * S_ + s0 + 32 + vsw * 8);
      }
    }

    // ---- QK^T: rg's 16 rows x h's 16 cols, full K=512 (2 indep chains) ----
    floatx4 Sa = {0.f, 0.f, 0.f, 0.f}, Sb = Sa;
#pragma unroll
    for (int kk = 0; kk < 8; ++kk) {
      int slot = (kk * 4 + qd) ^ n7;
      half8 bk = *(const half8*)&Klds[cur][h * 16 + n][slot * 8];
      Sa = mfma16(qreg[kk], bk, Sa);
    }
#pragma unroll
    for (int kk = 8; kk < 16; ++kk) {
      int slot = (kk * 4 + qd) ^ n7;
      half8 bk = *(const half8*)&Klds[cur][h * 16 + n][slot * 8];
      Sb = mfma16(qreg[kk], bk, Sb);
    }
    floatx4 Sc = Sa + Sb;

    // ---- pre-barrier: local max, local-scaled P, publish mloc + Mrun ----
    float mloc[4];
#pragma unroll
    for (int r = 0; r < 4; ++r) {
      float v = Sc[r];
      v = fmaxf(v, __shfl_xor(v, 1, 16));
      v = fmaxf(v, __shfl_xor(v, 2, 16));
      v = fmaxf(v, __shfl_xor(v, 4, 16));
      v = fmaxf(v, __shfl_xor(v, 8, 16));
      mloc[r] = v;
      if (n == qd * 4 + r) Mscr[rg][h][n] = v;  // row qd*4+r == n
    }
#pragma unroll
    for (int r = 0; r < 4; ++r) {
      float p = __expf(Sc[r] - mloc[r]);   // <= 1, fp16-safe
      Pscr[rg][qd * 4 + r][h * 16 + n] = (_Float16)p;
    }
    if (h == 0 && qd == 0) Mrun[rg][n] = muL;  // last tile's running max
    bar_lds();  // single exchange barrier (prefetch stays in flight)

    // ---- post-barrier: pair-consistent defer-max from SHARED values ----
    const float m0 = Mscr[rg][0][n];
    const float m1 = Mscr[rg][1][n];
    const float mr = Mrun[rg][n];
    const float mx = fmaxf(m0, m1);
    const bool fire = __any(mx - mr > 8.f);
    const float mu = fire ? fmaxf(mr, mx) : mr;   // m_used for row n
    muL = mu;

    if (fire) {
#pragma unroll
      for (int r = 0; r < 4; ++r) {
        float mnr = __shfl(mu, qd * 4 + r, 16);   // m_used for row qd*4+r
        float al = __expf(m_st[r] - mnr);
        m_st[r] = mnr;
#pragma unroll
        for (int ng = 0; ng < 17; ++ng) O[ng][r] *= al;
      }
    }

    // ---- PV: av = P_loc fragment, folded scale e^{mloc_h' - mu} ----
    half8 av = *(const half8*)&Pscr[rg][n][qd * 8];
    {
      float mh = (qd < 2) ? m0 : m1;              // av chunk's source half
      _Float16 hs = (_Float16)__expf(mh - mu);    // <= e^8, fp16-safe
      av = av * hs;
    }
#pragma unroll
    for (int ng = 0; ng < 16; ++ng) {
      half8 bv = *(const half8*)&Vlds[cur][h * 256 + ng * 16 + n][ccV * 8];
      O[ng] = mfma16(av, bv, O[ng]);
    }
    O[16] = mfma16(av, ones8, O[16]);

    if (st < S_ / 32 - 1) __syncthreads();  // swap buffers (drains prefetch)
  }

  // ---- epilogue: out = O / l for this wave's 256-d half ----
  float* ob = out + ((size_t)b * T_ + t0 + rg * 16) * D_ + h * 256;
#pragma unroll
  for (int r = 0; r < 4; ++r) {
    float inv = 1.f / O[16][r];
    const size_t rowoff = (size_t)(qd * 4 + r) * D_;
#pragma unroll
    for (int ng = 0; ng < 16; ++ng)
      ob[rowoff + ng * 16 + n] = O[ng][r] * inv;
  }
}

// ---------------------------------------------------------------------------
extern "C" void kernel_launch(void* const* d_in, const int* in_sizes, int n_in,
                              void* d_out, int out_size, void* d_ws, size_t ws_size,
                              hipStream_t stream) {
  (void)in_sizes; (void)n_in; (void)out_size; (void)ws_size;
  const float* main_in = (const float*)d_in[0];   // [B,T,D]
  const float* attn_in = (const float*)d_in[1];   // [B,S,D]
  const float* W_f     = (const float*)d_in[2];   // [D,D]
  const float* b_f     = (const float*)d_in[3];   // [D]
  float* out = (float*)d_out;                     // [B,T,D] fp32

  _Float16* K16 = (_Float16*)d_ws;                       // [B*S, D] fp16
  _Float16* Vt  = K16 + (size_t)B_ * S_ * D_;            // [B, D, S] fp16

  transpose_cast_kernel<<<dim3(D_ / 32, S_ / 32, B_), dim3(32, 8, 1), 0, stream>>>(
      attn_in, Vt);
  keys_gemm_kernel<<<dim3((B_ * S_) / 128, D_ / 128), 512, 0, stream>>>(
      attn_in, W_f, b_f, K16);
  flash_kernel<<<(B_ * T_) / 64, 512, 0, stream>>>(main_in, K16, Vt, out);
}